// Round 6
// baseline (400.365 us; speedup 1.0000x reference)
//
#include <hip/hip_runtime.h>
#include <stdint.h>

// SGRSelector: per-row exact top-K indices, sorted (value desc, idx asc).
// B=256, S=131072, K=16384. Output int32 [B,K] ++ scalar K.
//
// Pipeline:
//  A hist   : 4 blocks/row, per-quarter 8192-bin LDS histogram of top-13 bits.
//  B scan   : per row: merge quarters, SUFFIX scan (shuffle-based, ~4 barriers)
//             -> arr[], threshold bucket b1, heavy/light worklists, scalar K.
//  C gather : per (row, 1/8): pass1 count selected per bucket in LDS;
//             bulk-reserve ranges with ONE atomicSub per bucket; pass2 re-read
//             (L2-hot), LDS-allocate slot, write 49-bit key densely.
//  D sort   : dynamic work-stealing over worklists, heavy first. Per bucket:
//             rank needs only low-28 key bits (u32) + 8-bit digit (top 13 bits
//             constant within bucket) -> 22 KiB LDS, 7 blocks/CU.
//             Keys unique -> rank-by-count exact. Max bucket <= 4096 (R3).

#define S_LEN   131072
#define K_SEL   16384
#define NBINS   8192          // 2^13 buckets on top-13 bits
#define LOWBITS 19
#define IDXMASK 0x1FFFFu      // 17 bits of index
#define NCH_H   4
#define HCHUNK  (S_LEN / NCH_H)    // 32768
#define NCH_G   8
#define GCHUNK  (S_LEN / NCH_G)    // 16384
#define CAND_CAP 20480        // >= suffix[b1] ~ 18100
#define SORT_CAP 4096
#define DIRECT_MAX 256
#define WL_PER_ROW 2048
#define D_GRID  2048

__device__ __forceinline__ unsigned int ordered_u32(float f) {
  // Monotonic float->uint: larger float => larger uint.
  unsigned int x = __float_as_uint(f);
  unsigned int mask = (unsigned int)((int)x >> 31) | 0x80000000u;
  return x ^ mask;
}

// ---------- A: per-(row,quarter) histogram ----------
__global__ __launch_bounds__(1024)
void hist_kernel(const float* __restrict__ in, unsigned int* __restrict__ histA) {
  const int row = blockIdx.x / NCH_H;
  const int ch  = blockIdx.x % NCH_H;
  const int tid = threadIdx.x;
  __shared__ unsigned int h[NBINS];
  for (int i = tid; i < NBINS; i += 1024) h[i] = 0;
  __syncthreads();
  const float4* p = (const float4*)(in + (size_t)row * S_LEN + (size_t)ch * HCHUNK);
#pragma unroll 8
  for (int it = 0; it < HCHUNK / 4 / 1024; ++it) {
    float4 v = p[it * 1024 + tid];
    atomicAdd(&h[ordered_u32(v.x) >> LOWBITS], 1u);
    atomicAdd(&h[ordered_u32(v.y) >> LOWBITS], 1u);
    atomicAdd(&h[ordered_u32(v.z) >> LOWBITS], 1u);
    atomicAdd(&h[ordered_u32(v.w) >> LOWBITS], 1u);
  }
  __syncthreads();
  unsigned int* dst = histA + (size_t)blockIdx.x * NBINS;
  for (int i = tid; i < NBINS; i += 1024) dst[i] = h[i];
}

// ---------- B: merge + shuffle suffix scan + heavy/light worklists ----------
// ctrs: [0]=heavyCount [1]=lightCount [2]=heavyNext [3]=lightNext
__global__ __launch_bounds__(1024)
void scan_kernel(const unsigned int* __restrict__ histA, unsigned int* __restrict__ arr,
                 unsigned int* __restrict__ meta, uint4* __restrict__ wl,
                 unsigned int* __restrict__ ctrs, unsigned int wlHalf,
                 int* __restrict__ out, int B, long long out_size) {
  const int row  = blockIdx.x;
  const int tid  = threadIdx.x;
  const int lane = tid & 63, wave = tid >> 6;   // 16 waves
  __shared__ unsigned int sfx[NBINS];
  __shared__ unsigned int waveTot[16];
  __shared__ unsigned int sb1;
  const unsigned int* h0 = histA + (size_t)(row * NCH_H) * NBINS;

  // thread t owns bins [8t, 8t+8)
  unsigned int v[8];
#pragma unroll
  for (int s = 0; s < 8; ++s) {
    int b = tid * 8 + s;
    v[s] = h0[b] + h0[NBINS + b] + h0[2 * NBINS + b] + h0[3 * NBINS + b];
  }
#pragma unroll
  for (int s = 6; s >= 0; --s) v[s] += v[s + 1];      // local suffix
  unsigned int tot = v[0];
  // suffix over thread totals: within-wave via shuffles
  unsigned int suf = tot;
#pragma unroll
  for (int d = 1; d < 64; d <<= 1) {
    unsigned int o = __shfl_down(suf, d, 64);
    if (lane + d < 64) suf += o;
  }
  if (lane == 0) waveTot[wave] = suf;
  __syncthreads();
  unsigned int carry = 0;
  for (int w2 = wave + 1; w2 < 16; ++w2) carry += waveTot[w2];
  unsigned int addv = (suf - tot) + carry;            // from all higher threads
#pragma unroll
  for (int s = 0; s < 8; ++s) sfx[tid * 8 + s] = v[s] + addv;
  __syncthreads();
  // threshold bucket: unique b with sfx[b] >= K > sfx[b+1]
#pragma unroll
  for (int s = 0; s < 8; ++s) {
    int b = tid * 8 + s;
    unsigned int cur = sfx[b];
    unsigned int nxt = (b + 1 < NBINS) ? sfx[b + 1] : 0u;
    if (cur >= K_SEL && nxt < K_SEL) sb1 = (unsigned int)b;
  }
  __syncthreads();
  const unsigned int b1 = sb1;
  unsigned int* a = arr + (size_t)row * NBINS;
  for (int i = tid; i < NBINS; i += 1024) a[i] = sfx[i];
  // worklists: non-empty buckets >= b1 (start = sfx[b+1] < K for b >= b1)
  for (unsigned int b = b1 + (unsigned int)tid; b < NBINS; b += 1024) {
    unsigned int end   = sfx[b];
    unsigned int start = (b + 1 < NBINS) ? sfx[b + 1] : 0u;
    unsigned int cnt   = end - start;
    if (cnt) {
      if (cnt > DIRECT_MAX) {
        unsigned int pos = atomicAdd(&ctrs[0], 1u);
        if (pos < wlHalf) wl[2 * wlHalf - 1 - pos] = make_uint4((unsigned int)row, start, end, 0u);
      } else {
        unsigned int pos = atomicAdd(&ctrs[1], 1u);
        if (pos < wlHalf) wl[pos] = make_uint4((unsigned int)row, start, end, 0u);
      }
    }
  }
  if (tid == 0) {
    meta[row] = b1;
    if (row == 0) {
      long long pos = (long long)B * K_SEL;
      if (pos < out_size) out[pos] = K_SEL;
    }
  }
}

// ---------- C: two-pass gather, bulk range reservation ----------
__global__ __launch_bounds__(1024)
void gather_kernel(const float* __restrict__ in, unsigned int* __restrict__ arr,
                   const unsigned int* __restrict__ meta,
                   unsigned long long* __restrict__ cand) {
  const int row   = blockIdx.x / NCH_G;
  const int chunk = blockIdx.x % NCH_G;
  const int tid   = threadIdx.x;
  const unsigned int b1 = meta[row];
  unsigned int* a = arr + (size_t)row * NBINS;
  unsigned long long* c = cand + (size_t)row * CAND_CAP;
  const int base = chunk * GCHUNK;
  const float4* p = (const float4*)(in + (size_t)row * S_LEN + base);

  __shared__ unsigned int hcnt[NBINS];   // counts, then alloc cursors
  for (int i = tid; i < NBINS; i += 1024) hcnt[i] = 0;
  __syncthreads();
  // pass 1: count selected per bucket
#pragma unroll 4
  for (int it = 0; it < GCHUNK / 4 / 1024; ++it) {
    float4 v = p[it * 1024 + tid];
    float f[4] = {v.x, v.y, v.z, v.w};
#pragma unroll
    for (int e = 0; e < 4; ++e) {
      unsigned int b = ordered_u32(f[e]) >> LOWBITS;
      if (b >= b1) atomicAdd(&hcnt[b], 1u);
    }
  }
  __syncthreads();
  // bulk-reserve: one global atomic per non-empty bucket
  for (unsigned int b = b1 + (unsigned int)tid; b < NBINS; b += 1024) {
    unsigned int cnt = hcnt[b];
    if (cnt) hcnt[b] = atomicSub(&a[b], cnt) - cnt;   // range start cursor
  }
  __syncthreads();
  // pass 2: re-read (L2-hot), LDS-allocate, dense key write
#pragma unroll 4
  for (int it = 0; it < GCHUNK / 4 / 1024; ++it) {
    int i4 = it * 1024 + tid;
    float4 v = p[i4];
    int idx0 = base + i4 * 4;
    float f[4] = {v.x, v.y, v.z, v.w};
#pragma unroll
    for (int e = 0; e < 4; ++e) {
      unsigned int u = ordered_u32(f[e]);
      unsigned int b = u >> LOWBITS;
      if (b >= b1) {
        unsigned int pos = atomicAdd(&hcnt[b], 1u);
        unsigned long long key =                       // 49-bit key, unique
            ((unsigned long long)u << 17) |
            (unsigned long long)(IDXMASK - (unsigned int)(idx0 + e));
        if (pos < CAND_CAP) c[pos] = key;
      }
    }
  }
}

// ---------- D: work-stealing per-bucket exact ranking, compact keys ----------
__global__ __launch_bounds__(256)
void sort_kernel(const uint4* __restrict__ wl, unsigned int* __restrict__ ctrs,
                 unsigned int wlHalf, const unsigned long long* __restrict__ cand,
                 int* __restrict__ out) {
  const int tid  = threadIdx.x;            // 256 threads, 4 waves
  const int lane = tid & 63, wave = tid >> 6;
  __shared__ unsigned int   skey2[SORT_CAP];   // 16 KiB: low-28 key bits
  __shared__ unsigned char  sdig2[SORT_CAP];   //  4 KiB: 8-bit digit
  __shared__ unsigned int   ssfx[257];
  __shared__ unsigned int   scur[256];
  __shared__ unsigned int   segTot[4];
  __shared__ unsigned int   sW;
  unsigned int nHeavy = ctrs[0]; if (nHeavy > wlHalf) nHeavy = wlHalf;
  unsigned int nLight = ctrs[1]; if (nLight > wlHalf) nLight = wlHalf;

  // ---- heavy phase (count > DIRECT_MAX): radix digit + sub-bucket rank ----
  for (;;) {
    if (tid == 0) sW = atomicAdd(&ctrs[2], 1u);
    __syncthreads();
    unsigned int w = sW;
    __syncthreads();
    if (w >= nHeavy) break;
    const uint4 it = wl[2 * wlHalf - 1 - w];
    const unsigned int row = it.x, start = it.y;
    unsigned int count = it.z - start;
    if (count > SORT_CAP) count = SORT_CAP;      // proven never hit (R3)
    const unsigned long long* c = cand + (size_t)row * CAND_CAP + start;
    int* orow = out + (size_t)row * K_SEL;

    scur[tid] = 0;
    __syncthreads();
    for (unsigned int i = tid; i < count; i += 256)
      atomicAdd(&scur[(unsigned int)(c[i] >> 28) & 255u], 1u);
    __syncthreads();
    // 256-digit suffix scan via shuffles (digit = tid)
    unsigned int cnt = scur[tid];
    unsigned int suf = cnt;
#pragma unroll
    for (int d = 1; d < 64; d <<= 1) {
      unsigned int o = __shfl_down(suf, d, 64);
      if (lane + d < 64) suf += o;
    }
    if (lane == 0) segTot[wave] = suf;
    __syncthreads();
    unsigned int carry = 0;
    for (int w2 = wave + 1; w2 < 4; ++w2) carry += segTot[w2];
    ssfx[tid] = suf + carry;                     // # elements with digit >= tid
    if (tid == 0) ssfx[256] = 0;
    __syncthreads();
    scur[tid] = ssfx[tid + 1];                   // digit range start cursor
    __syncthreads();
    // scatter by digit; keep only low-28 bits + digit
    for (unsigned int i = tid; i < count; i += 256) {
      unsigned long long k = c[i];
      unsigned int d = (unsigned int)(k >> 28) & 255u;
      unsigned int p = atomicAdd(&scur[d], 1u);
      skey2[p] = (unsigned int)k & 0x0FFFFFFFu;
      sdig2[p] = (unsigned char)d;
    }
    __syncthreads();
    // exact rank within sub-bucket (keys unique; same digit -> low28 decides)
    for (unsigned int p = tid; p < count; p += 256) {
      unsigned int k = skey2[p];
      unsigned int d = sdig2[p];
      unsigned int lo = ssfx[d + 1], hi = ssfx[d];
      unsigned int r = 0;
      for (unsigned int q = lo; q < hi; ++q) r += (skey2[q] > k) ? 1u : 0u;
      unsigned int pos = start + lo + r;
      if (pos < K_SEL)
        orow[pos] = (int)(IDXMASK - (k & IDXMASK));
    }
    __syncthreads();
  }

  // ---- light phase (count <= 256): direct O(m^2) rank ----
  for (;;) {
    if (tid == 0) sW = atomicAdd(&ctrs[3], 1u);
    __syncthreads();
    unsigned int w = sW;
    __syncthreads();
    if (w >= nLight) break;
    const uint4 it = wl[w];
    const unsigned int row = it.x, start = it.y;
    const unsigned int count = it.z - start;
    const unsigned long long* c = cand + (size_t)row * CAND_CAP + start;
    int* orow = out + (size_t)row * K_SEL;
    unsigned int mykey = 0, mydig = 0;
    if (tid < (int)count) {
      unsigned long long k = c[tid];
      mykey = (unsigned int)k & 0x0FFFFFFFu;
      mydig = (unsigned int)(k >> 28) & 255u;
      skey2[tid] = mykey;
      sdig2[tid] = (unsigned char)mydig;
    }
    __syncthreads();
    if (tid < (int)count) {
      unsigned long long me = ((unsigned long long)mydig << 28) | mykey;
      unsigned int r = 0;
      for (unsigned int j = 0; j < count; ++j) {
        unsigned long long kj = ((unsigned long long)sdig2[j] << 28) | skey2[j];
        r += (kj > me) ? 1u : 0u;
      }
      unsigned int pos = start + r;
      if (pos < K_SEL)
        orow[pos] = (int)(IDXMASK - (mykey & IDXMASK));
    }
    __syncthreads();
  }
}

extern "C" void kernel_launch(void* const* d_in, const int* in_sizes, int n_in,
                              void* d_out, int out_size, void* d_ws, size_t ws_size,
                              hipStream_t stream) {
  const float* importance = (const float*)d_in[0];
  int B = in_sizes[0] / S_LEN;
  if (B < 1) B = 1;
  (void)n_in; (void)ws_size;

  const unsigned int wlCap  = (unsigned int)B * WL_PER_ROW;   // total uint4 slots
  const unsigned int wlHalf = wlCap / 2;
  size_t histBytes = (size_t)B * NCH_H * NBINS * sizeof(unsigned int);    // 32 MB
  size_t arrBytes  = (size_t)B * NBINS * sizeof(unsigned int);            //  8 MB
  size_t candBytes = (size_t)B * CAND_CAP * sizeof(unsigned long long);   // 40 MB
  size_t wlBytes   = (size_t)wlCap * sizeof(uint4);                       //  8 MB
  char* base = (char*)d_ws;
  unsigned int* histA      = (unsigned int*)base;
  unsigned int* arr        = (unsigned int*)(base + histBytes);
  unsigned long long* cand = (unsigned long long*)(base + histBytes + arrBytes);
  uint4* wl                = (uint4*)(base + histBytes + arrBytes + candBytes);
  unsigned int* meta       = (unsigned int*)(base + histBytes + arrBytes + candBytes + wlBytes);
  unsigned int* ctrs       = meta + B;   // 4 counters
  int* out = (int*)d_out;

  hipMemsetAsync(ctrs, 0, 4 * sizeof(unsigned int), stream);
  hist_kernel  <<<dim3(B * NCH_H), dim3(1024), 0, stream>>>(importance, histA);
  scan_kernel  <<<dim3(B),         dim3(1024), 0, stream>>>(
      histA, arr, meta, wl, ctrs, wlHalf, out, B, (long long)out_size);
  gather_kernel<<<dim3(B * NCH_G), dim3(1024), 0, stream>>>(importance, arr, meta, cand);
  sort_kernel  <<<dim3(D_GRID),    dim3(256),  0, stream>>>(wl, ctrs, wlHalf, cand, out);
}

// Round 7
// 298.047 us; speedup vs baseline: 1.3433x; 1.3433x over previous
//
#include <hip/hip_runtime.h>
#include <stdint.h>

// SGRSelector: per-row exact top-K indices, sorted (value desc, idx asc).
// B=256, S=131072, K=16384. Output int32 [B,K] ++ scalar K.
//
// Pipeline:
//  A hist   : 4 blocks/row, per-quarter 8192-bin LDS histogram of top-13 bits.
//  B scan   : per row: merge quarters, shuffle-based SUFFIX scan -> arr[],
//             threshold bucket b1, heavy/light worklists, scalar K.
//  C gather : per (row, 1/8): pass1 count selected per bucket in LDS;
//             bulk-reserve ranges with ONE atomicSub per bucket; pass2 re-read
//             (L2-hot), LDS-allocate slot, write 49-bit key densely.
//  D sort   : STATIC grid-stride (R6's single-counter work-stealing caused
//             cross-XCD atomic ping-pong — reverted). Heavy buckets: block-level
//             radix digit + sub-bucket exact rank (compact u32 keys in LDS).
//             Light buckets (<=256): one per WAVE, register-only rank via
//             __shfl broadcasts — no LDS, no barriers, 4 in flight per block.
//             Keys unique -> rank-by-count exact. Max bucket <= 4096 (R3).

#define S_LEN   131072
#define K_SEL   16384
#define NBINS   8192          // 2^13 buckets on top-13 bits
#define LOWBITS 19
#define IDXMASK 0x1FFFFu      // 17 bits of index
#define NCH_H   4
#define HCHUNK  (S_LEN / NCH_H)    // 32768
#define NCH_G   8
#define GCHUNK  (S_LEN / NCH_G)    // 16384
#define CAND_CAP 20480        // >= suffix[b1] ~ 18100
#define SORT_CAP 4096
#define DIRECT_MAX 256
#define WL_PER_ROW 2048
#define D_GRID  2048

__device__ __forceinline__ unsigned int ordered_u32(float f) {
  // Monotonic float->uint: larger float => larger uint.
  unsigned int x = __float_as_uint(f);
  unsigned int mask = (unsigned int)((int)x >> 31) | 0x80000000u;
  return x ^ mask;
}

// ---------- A: per-(row,quarter) histogram ----------
__global__ __launch_bounds__(1024)
void hist_kernel(const float* __restrict__ in, unsigned int* __restrict__ histA) {
  const int row = blockIdx.x / NCH_H;
  const int ch  = blockIdx.x % NCH_H;
  const int tid = threadIdx.x;
  __shared__ unsigned int h[NBINS];
  for (int i = tid; i < NBINS; i += 1024) h[i] = 0;
  __syncthreads();
  const float4* p = (const float4*)(in + (size_t)row * S_LEN + (size_t)ch * HCHUNK);
#pragma unroll 8
  for (int it = 0; it < HCHUNK / 4 / 1024; ++it) {
    float4 v = p[it * 1024 + tid];
    atomicAdd(&h[ordered_u32(v.x) >> LOWBITS], 1u);
    atomicAdd(&h[ordered_u32(v.y) >> LOWBITS], 1u);
    atomicAdd(&h[ordered_u32(v.z) >> LOWBITS], 1u);
    atomicAdd(&h[ordered_u32(v.w) >> LOWBITS], 1u);
  }
  __syncthreads();
  unsigned int* dst = histA + (size_t)blockIdx.x * NBINS;
  for (int i = tid; i < NBINS; i += 1024) dst[i] = h[i];
}

// ---------- B: merge + shuffle suffix scan + heavy/light worklists ----------
// ctrs: [0]=heavyCount [1]=lightCount
__global__ __launch_bounds__(1024)
void scan_kernel(const unsigned int* __restrict__ histA, unsigned int* __restrict__ arr,
                 unsigned int* __restrict__ meta, uint4* __restrict__ wl,
                 unsigned int* __restrict__ ctrs, unsigned int wlHalf,
                 int* __restrict__ out, int B, long long out_size) {
  const int row  = blockIdx.x;
  const int tid  = threadIdx.x;
  const int lane = tid & 63, wave = tid >> 6;   // 16 waves
  __shared__ unsigned int sfx[NBINS];
  __shared__ unsigned int waveTot[16];
  __shared__ unsigned int sb1;
  const unsigned int* h0 = histA + (size_t)(row * NCH_H) * NBINS;

  // thread t owns bins [8t, 8t+8)
  unsigned int v[8];
#pragma unroll
  for (int s = 0; s < 8; ++s) {
    int b = tid * 8 + s;
    v[s] = h0[b] + h0[NBINS + b] + h0[2 * NBINS + b] + h0[3 * NBINS + b];
  }
#pragma unroll
  for (int s = 6; s >= 0; --s) v[s] += v[s + 1];      // local suffix
  unsigned int tot = v[0];
  unsigned int suf = tot;
#pragma unroll
  for (int d = 1; d < 64; d <<= 1) {
    unsigned int o = __shfl_down(suf, d, 64);
    if (lane + d < 64) suf += o;
  }
  if (lane == 0) waveTot[wave] = suf;
  __syncthreads();
  unsigned int carry = 0;
  for (int w2 = wave + 1; w2 < 16; ++w2) carry += waveTot[w2];
  unsigned int addv = (suf - tot) + carry;            // from all higher threads
#pragma unroll
  for (int s = 0; s < 8; ++s) sfx[tid * 8 + s] = v[s] + addv;
  __syncthreads();
#pragma unroll
  for (int s = 0; s < 8; ++s) {
    int b = tid * 8 + s;
    unsigned int cur = sfx[b];
    unsigned int nxt = (b + 1 < NBINS) ? sfx[b + 1] : 0u;
    if (cur >= K_SEL && nxt < K_SEL) sb1 = (unsigned int)b;
  }
  __syncthreads();
  const unsigned int b1 = sb1;
  unsigned int* a = arr + (size_t)row * NBINS;
  for (int i = tid; i < NBINS; i += 1024) a[i] = sfx[i];
  // worklists: non-empty buckets >= b1 (start = sfx[b+1] < K for b >= b1)
  for (unsigned int b = b1 + (unsigned int)tid; b < NBINS; b += 1024) {
    unsigned int end   = sfx[b];
    unsigned int start = (b + 1 < NBINS) ? sfx[b + 1] : 0u;
    unsigned int cnt   = end - start;
    if (cnt) {
      if (cnt > DIRECT_MAX) {
        unsigned int pos = atomicAdd(&ctrs[0], 1u);
        if (pos < wlHalf) wl[2 * wlHalf - 1 - pos] = make_uint4((unsigned int)row, start, end, 0u);
      } else {
        unsigned int pos = atomicAdd(&ctrs[1], 1u);
        if (pos < wlHalf) wl[pos] = make_uint4((unsigned int)row, start, end, 0u);
      }
    }
  }
  if (tid == 0) {
    meta[row] = b1;
    if (row == 0) {
      long long pos = (long long)B * K_SEL;
      if (pos < out_size) out[pos] = K_SEL;
    }
  }
}

// ---------- C: two-pass gather, bulk range reservation ----------
__global__ __launch_bounds__(1024)
void gather_kernel(const float* __restrict__ in, unsigned int* __restrict__ arr,
                   const unsigned int* __restrict__ meta,
                   unsigned long long* __restrict__ cand) {
  const int row   = blockIdx.x / NCH_G;
  const int chunk = blockIdx.x % NCH_G;
  const int tid   = threadIdx.x;
  const unsigned int b1 = meta[row];
  unsigned int* a = arr + (size_t)row * NBINS;
  unsigned long long* c = cand + (size_t)row * CAND_CAP;
  const int base = chunk * GCHUNK;
  const float4* p = (const float4*)(in + (size_t)row * S_LEN + base);

  __shared__ unsigned int hcnt[NBINS];   // counts, then alloc cursors
  for (int i = tid; i < NBINS; i += 1024) hcnt[i] = 0;
  __syncthreads();
  // pass 1: count selected per bucket
#pragma unroll 4
  for (int it = 0; it < GCHUNK / 4 / 1024; ++it) {
    float4 v = p[it * 1024 + tid];
    float f[4] = {v.x, v.y, v.z, v.w};
#pragma unroll
    for (int e = 0; e < 4; ++e) {
      unsigned int b = ordered_u32(f[e]) >> LOWBITS;
      if (b >= b1) atomicAdd(&hcnt[b], 1u);
    }
  }
  __syncthreads();
  // bulk-reserve: one global atomic per non-empty bucket
  for (unsigned int b = b1 + (unsigned int)tid; b < NBINS; b += 1024) {
    unsigned int cnt = hcnt[b];
    if (cnt) hcnt[b] = atomicSub(&a[b], cnt) - cnt;   // range start cursor
  }
  __syncthreads();
  // pass 2: re-read (L2-hot), LDS-allocate, dense key write
#pragma unroll 4
  for (int it = 0; it < GCHUNK / 4 / 1024; ++it) {
    int i4 = it * 1024 + tid;
    float4 v = p[i4];
    int idx0 = base + i4 * 4;
    float f[4] = {v.x, v.y, v.z, v.w};
#pragma unroll
    for (int e = 0; e < 4; ++e) {
      unsigned int u = ordered_u32(f[e]);
      unsigned int b = u >> LOWBITS;
      if (b >= b1) {
        unsigned int pos = atomicAdd(&hcnt[b], 1u);
        unsigned long long key =                       // 49-bit key, unique
            ((unsigned long long)u << 17) |
            (unsigned long long)(IDXMASK - (unsigned int)(idx0 + e));
        if (pos < CAND_CAP) c[pos] = key;
      }
    }
  }
}

// ---------- D: static-stride per-bucket exact ranking ----------
__global__ __launch_bounds__(256)
void sort_kernel(const uint4* __restrict__ wl, const unsigned int* __restrict__ ctrs,
                 unsigned int wlHalf, const unsigned long long* __restrict__ cand,
                 int* __restrict__ out) {
  const int tid  = threadIdx.x;            // 256 threads, 4 waves
  const int lane = tid & 63, wave = tid >> 6;
  __shared__ unsigned int   skey2[SORT_CAP];   // 16 KiB: low-28 key bits
  __shared__ unsigned char  sdig2[SORT_CAP];   //  4 KiB: 8-bit digit
  __shared__ unsigned int   ssfx[257];
  __shared__ unsigned int   scur[256];
  __shared__ unsigned int   segTot[4];
  unsigned int nHeavy = ctrs[0]; if (nHeavy > wlHalf) nHeavy = wlHalf;
  unsigned int nLight = ctrs[1]; if (nLight > wlHalf) nLight = wlHalf;

  // ---- heavy phase (count > 256): block-level radix digit + sub-bucket rank ----
  for (unsigned int w = blockIdx.x; w < nHeavy; w += gridDim.x) {
    const uint4 it = wl[2 * wlHalf - 1 - w];
    const unsigned int row = it.x, start = it.y;
    unsigned int count = it.z - start;
    if (count > SORT_CAP) count = SORT_CAP;      // proven never hit (R3)
    const unsigned long long* c = cand + (size_t)row * CAND_CAP + start;
    int* orow = out + (size_t)row * K_SEL;

    scur[tid] = 0;
    __syncthreads();
    for (unsigned int i = tid; i < count; i += 256)
      atomicAdd(&scur[(unsigned int)(c[i] >> 28) & 255u], 1u);
    __syncthreads();
    // 256-digit suffix scan via shuffles (digit = tid)
    unsigned int cnt = scur[tid];
    unsigned int suf = cnt;
#pragma unroll
    for (int d = 1; d < 64; d <<= 1) {
      unsigned int o = __shfl_down(suf, d, 64);
      if (lane + d < 64) suf += o;
    }
    if (lane == 0) segTot[wave] = suf;
    __syncthreads();
    unsigned int carry = 0;
    for (int w2 = wave + 1; w2 < 4; ++w2) carry += segTot[w2];
    ssfx[tid] = suf + carry;                     // # elements with digit >= tid
    if (tid == 0) ssfx[256] = 0;
    __syncthreads();
    scur[tid] = ssfx[tid + 1];                   // digit range start cursor
    __syncthreads();
    // scatter by digit; keep only low-28 bits + digit
    for (unsigned int i = tid; i < count; i += 256) {
      unsigned long long k = c[i];
      unsigned int d = (unsigned int)(k >> 28) & 255u;
      unsigned int p = atomicAdd(&scur[d], 1u);
      skey2[p] = (unsigned int)k & 0x0FFFFFFFu;
      sdig2[p] = (unsigned char)d;
    }
    __syncthreads();
    // exact rank within sub-bucket (keys unique; same digit -> low28 decides)
    for (unsigned int p = tid; p < count; p += 256) {
      unsigned int k = skey2[p];
      unsigned int d = sdig2[p];
      unsigned int lo = ssfx[d + 1], hi = ssfx[d];
      unsigned int r = 0;
      for (unsigned int q = lo; q < hi; ++q) r += (skey2[q] > k) ? 1u : 0u;
      unsigned int pos = start + lo + r;
      if (pos < K_SEL)
        orow[pos] = (int)(IDXMASK - (k & IDXMASK));
    }
    __syncthreads();
  }

  // ---- light phase (count <= 256): one item per WAVE, register-only rank ----
  for (unsigned int w = blockIdx.x * 4u + (unsigned int)wave; w < nLight;
       w += gridDim.x * 4u) {
    const uint4 it = wl[w];
    const unsigned int row = it.x, start = it.y;
    const unsigned int count = it.z - start;     // <= 256 = 4 keys/lane
    const unsigned long long* c = cand + (size_t)row * CAND_CAP + start;
    int* orow = out + (size_t)row * K_SEL;
    unsigned long long me[4];
#pragma unroll
    for (int e = 0; e < 4; ++e) {
      unsigned int i = (unsigned int)lane + 64u * e;
      me[e] = (i < count) ? c[i] : 0ull;         // real keys > 0 always
    }
    unsigned int r[4] = {0u, 0u, 0u, 0u};
#pragma unroll
    for (int e = 0; e < 4; ++e) {
      for (int l = 0; l < 64; ++l) {
        unsigned long long kj = __shfl(me[e], l, 64);
#pragma unroll
        for (int e2 = 0; e2 < 4; ++e2) r[e2] += (kj > me[e2]) ? 1u : 0u;
      }
    }
#pragma unroll
    for (int e = 0; e < 4; ++e) {
      unsigned int i = (unsigned int)lane + 64u * e;
      if (i < count) {
        unsigned int pos = start + r[e];
        if (pos < K_SEL)
          orow[pos] = (int)(IDXMASK - ((unsigned int)me[e] & IDXMASK));
      }
    }
  }
}

extern "C" void kernel_launch(void* const* d_in, const int* in_sizes, int n_in,
                              void* d_out, int out_size, void* d_ws, size_t ws_size,
                              hipStream_t stream) {
  const float* importance = (const float*)d_in[0];
  int B = in_sizes[0] / S_LEN;
  if (B < 1) B = 1;
  (void)n_in; (void)ws_size;

  const unsigned int wlCap  = (unsigned int)B * WL_PER_ROW;   // total uint4 slots
  const unsigned int wlHalf = wlCap / 2;
  size_t histBytes = (size_t)B * NCH_H * NBINS * sizeof(unsigned int);    // 32 MB
  size_t arrBytes  = (size_t)B * NBINS * sizeof(unsigned int);            //  8 MB
  size_t candBytes = (size_t)B * CAND_CAP * sizeof(unsigned long long);   // 40 MB
  size_t wlBytes   = (size_t)wlCap * sizeof(uint4);                       //  8 MB
  char* base = (char*)d_ws;
  unsigned int* histA      = (unsigned int*)base;
  unsigned int* arr        = (unsigned int*)(base + histBytes);
  unsigned long long* cand = (unsigned long long*)(base + histBytes + arrBytes);
  uint4* wl                = (uint4*)(base + histBytes + arrBytes + candBytes);
  unsigned int* meta       = (unsigned int*)(base + histBytes + arrBytes + candBytes + wlBytes);
  unsigned int* ctrs       = meta + B;   // 2 counters
  int* out = (int*)d_out;

  hipMemsetAsync(ctrs, 0, 4 * sizeof(unsigned int), stream);
  hist_kernel  <<<dim3(B * NCH_H), dim3(1024), 0, stream>>>(importance, histA);
  scan_kernel  <<<dim3(B),         dim3(1024), 0, stream>>>(
      histA, arr, meta, wl, ctrs, wlHalf, out, B, (long long)out_size);
  gather_kernel<<<dim3(B * NCH_G), dim3(1024), 0, stream>>>(importance, arr, meta, cand);
  sort_kernel  <<<dim3(D_GRID),    dim3(256),  0, stream>>>(wl, ctrs, wlHalf, cand, out);
}